// Round 2
// baseline (319.740 us; speedup 1.0000x reference)
//
#include <hip/hip_runtime.h>

#define NCELL 4096

// LDS weight layout (float offsets, all segment starts 16B-aligned)
#define W1O 0      // 63x32 = 2016
#define B1O 2016   // 32
#define W2O 2048   // 32x33 = 1056
#define B2O 3104   // 33 (pad to 36)
#define W3O 3140   // 32x32 = 1024
#define B3O 4164   // 32
#define W4O 4196   // 59x32 = 1888
#define B4O 6084   // 32
#define W5O 6116   // 32x3 = 96
#define B5O 6212   // 3 (pad to 4)
#define WTOT 6216

__device__ __forceinline__ int cell_of(float x0, float x1, float x2) {
    int i0 = (int)(x0 / 0.1875f + 8.0f);
    int i1 = (int)(x1 / 0.1875f + 8.0f);
    int i2 = (int)(x2 / 0.1875f + 8.0f);
    i0 = i0 < 0 ? 0 : (i0 > 15 ? 15 : i0);
    i1 = i1 < 0 ? 0 : (i1 > 15 ? 15 : i1);
    i2 = i2 < 0 ? 0 : (i2 > 15 ? 15 : i2);
    return (i0 * 16 + i1) * 16 + i2;
}

// Kernel 1: count active points per cell; write zeros for masked points.
__global__ void k_count(const float* __restrict__ xs, int* __restrict__ counts,
                        float* __restrict__ out, int P) {
    int p = blockIdx.x * blockDim.x + threadIdx.x;
    if (p >= P) return;
    float x0 = xs[p * 3 + 0], x1 = xs[p * 3 + 1], x2 = xs[p * 3 + 2];
    bool m = (fabsf(x0) < 1.5f) && (fabsf(x1) < 1.5f) && (fabsf(x2) < 1.5f);
    if (m) {
        atomicAdd(&counts[cell_of(x0, x1, x2)], 1);
    } else {
        out[p * 3 + 0] = 0.0f;
        out[p * 3 + 1] = 0.0f;
        out[p * 3 + 2] = 0.0f;
        out[3 * P + p] = 0.0f;
    }
}

// Kernel 2: exclusive prefix sum over 4096 cell counts (one wave).
__global__ void k_scan(const int* __restrict__ counts, int* __restrict__ offsets,
                       int* __restrict__ cursor) {
    int l = threadIdx.x;
    int base = l * 64;
    int s = 0;
    for (int k = 0; k < 64; k++) s += counts[base + k];
    int incl = s;
    for (int d = 1; d < 64; d <<= 1) {
        int v = __shfl_up(incl, d, 64);
        if (l >= d) incl += v;
    }
    int run = incl - s;
    for (int k = 0; k < 64; k++) {
        offsets[base + k] = run;
        cursor[base + k] = run;
        run += counts[base + k];
    }
    if (l == 63) offsets[4096] = run;
}

// Kernel 3: scatter active point indices into per-cell contiguous ranges.
__global__ void k_scatter(const float* __restrict__ xs, int* __restrict__ cursor,
                          int* __restrict__ sorted, int P) {
    int p = blockIdx.x * blockDim.x + threadIdx.x;
    if (p >= P) return;
    float x0 = xs[p * 3 + 0], x1 = xs[p * 3 + 1], x2 = xs[p * 3 + 2];
    bool m = (fabsf(x0) < 1.5f) && (fabsf(x1) < 1.5f) && (fabsf(x2) < 1.5f);
    if (!m) return;
    int c = cell_of(x0, x1, x2);
    int pos = atomicAdd(&cursor[c], 1);
    sorted[pos] = p;
}

__device__ __forceinline__ void stage4(float* __restrict__ dst,
                                       const float* __restrict__ src,
                                       int n4, int tid) {
    float4* d = (float4*)dst;
    const float4* s = (const float4*)src;
    for (int k = tid; k < n4; k += 64) d[k] = s[k];
}

// Kernel 4: one block (1 wave) per cell. Full weight set staged in LDS via
// deeply-pipelined coalesced float4 loads; compute reads weights from LDS
// (uniform broadcast, conflict-free). Activations fully in registers (all
// loops fully unrolled -> compile-time indices).
__global__ void __launch_bounds__(64) k_mlp(
    const float* __restrict__ xs, const float* __restrict__ dvs,
    const float* __restrict__ w1, const float* __restrict__ b1,
    const float* __restrict__ w2, const float* __restrict__ b2,
    const float* __restrict__ w3, const float* __restrict__ b3,
    const float* __restrict__ w4, const float* __restrict__ b4,
    const float* __restrict__ w5, const float* __restrict__ b5,
    const int* __restrict__ offsets, const int* __restrict__ sorted,
    float* __restrict__ out, int P) {
    __shared__ float w[WTOT];
    int cell = blockIdx.x;
    int start = offsets[cell], end = offsets[cell + 1];
    if (start >= end) return;
    int tid = threadIdx.x;

    stage4(&w[W1O], w1 + (size_t)cell * 2016, 504, tid);
    stage4(&w[B1O], b1 + (size_t)cell * 32, 8, tid);
    stage4(&w[W2O], w2 + (size_t)cell * 1056, 264, tid);
    for (int k = tid; k < 33; k += 64) w[B2O + k] = b2[(size_t)cell * 33 + k];
    stage4(&w[W3O], w3 + (size_t)cell * 1024, 256, tid);
    stage4(&w[B3O], b3 + (size_t)cell * 32, 8, tid);
    stage4(&w[W4O], w4 + (size_t)cell * 1888, 472, tid);
    stage4(&w[B4O], b4 + (size_t)cell * 32, 8, tid);
    stage4(&w[W5O], w5 + (size_t)cell * 96, 24, tid);
    if (tid < 3) w[B5O + tid] = b5[(size_t)cell * 3 + tid];
    __syncthreads();

    for (int t0 = start; t0 < end; t0 += 64) {
        int t = t0 + tid;
        bool valid = t < end;
        int idx = sorted[valid ? t : start];

        float x0 = xs[idx * 3 + 0], x1 = xs[idx * 3 + 1], x2 = xs[idx * 3 + 2];

        // positional encoding (63) -> registers
        float enc[63];
        enc[0] = x0; enc[1] = x1; enc[2] = x2;
#pragma unroll
        for (int j = 0; j < 10; j++) {
            float pw = (float)(1 << j);
            float a0 = pw * x0, a1 = pw * x1, a2 = pw * x2;
            enc[3 + 6 * j + 0] = __sinf(a0);
            enc[3 + 6 * j + 1] = __sinf(a1);
            enc[3 + 6 * j + 2] = __sinf(a2);
            enc[6 + 6 * j + 0] = __cosf(a0);
            enc[6 + 6 * j + 1] = __cosf(a1);
            enc[6 + 6 * j + 2] = __cosf(a2);
        }

        float h[33];
        // ---- layer 1: 63 -> 32, relu
#pragma unroll
        for (int o = 0; o < 32; o++) h[o] = w[B1O + o];
#pragma unroll
        for (int i = 0; i < 63; i++) {
            float e = enc[i];
#pragma unroll
            for (int o = 0; o < 32; o++) h[o] = fmaf(e, w[W1O + i * 32 + o], h[o]);
        }
#pragma unroll
        for (int o = 0; o < 32; o++) h[o] = fmaxf(h[o], 0.0f);

        // ---- layer 2: 32 -> 33, relu; [0] = sigma
        float g[33];
#pragma unroll
        for (int o = 0; o < 33; o++) g[o] = w[B2O + o];
#pragma unroll
        for (int i = 0; i < 32; i++) {
            float e = h[i];
#pragma unroll
            for (int o = 0; o < 33; o++) g[o] = fmaf(e, w[W2O + i * 33 + o], g[o]);
        }
        float sigma = fmaxf(g[0], 0.0f);
        float h2[32];
#pragma unroll
        for (int o = 0; o < 32; o++) h2[o] = fmaxf(g[o + 1], 0.0f);

        // ---- layer 3: 32 -> 32, no activation
        float h3[32];
#pragma unroll
        for (int o = 0; o < 32; o++) h3[o] = w[B3O + o];
#pragma unroll
        for (int i = 0; i < 32; i++) {
            float e = h2[i];
#pragma unroll
            for (int o = 0; o < 32; o++) h3[o] = fmaf(e, w[W3O + i * 32 + o], h3[o]);
        }

        // ---- direction encoding (27) -> registers
        float d0 = dvs[idx * 3 + 0], d1 = dvs[idx * 3 + 1], d2 = dvs[idx * 3 + 2];
        float ed[27];
        ed[0] = d0; ed[1] = d1; ed[2] = d2;
#pragma unroll
        for (int j = 0; j < 4; j++) {
            float pw = (float)(1 << j);
            float a0 = pw * d0, a1 = pw * d1, a2 = pw * d2;
            ed[3 + 6 * j + 0] = __sinf(a0);
            ed[3 + 6 * j + 1] = __sinf(a1);
            ed[3 + 6 * j + 2] = __sinf(a2);
            ed[6 + 6 * j + 0] = __cosf(a0);
            ed[6 + 6 * j + 1] = __cosf(a1);
            ed[6 + 6 * j + 2] = __cosf(a2);
        }

        // ---- layer 4: 59 (h3[32] ++ ed[27]) -> 32, relu
        float h4[32];
#pragma unroll
        for (int o = 0; o < 32; o++) h4[o] = w[B4O + o];
#pragma unroll
        for (int i = 0; i < 32; i++) {
            float e = h3[i];
#pragma unroll
            for (int o = 0; o < 32; o++) h4[o] = fmaf(e, w[W4O + i * 32 + o], h4[o]);
        }
#pragma unroll
        for (int i = 0; i < 27; i++) {
            float e = ed[i];
#pragma unroll
            for (int o = 0; o < 32; o++) h4[o] = fmaf(e, w[W4O + (32 + i) * 32 + o], h4[o]);
        }
#pragma unroll
        for (int o = 0; o < 32; o++) h4[o] = fmaxf(h4[o], 0.0f);

        // ---- layer 5: 32 -> 3, sigmoid
        float c0 = w[B5O + 0], c1 = w[B5O + 1], c2 = w[B5O + 2];
#pragma unroll
        for (int i = 0; i < 32; i++) {
            float e = h4[i];
            c0 = fmaf(e, w[W5O + i * 3 + 0], c0);
            c1 = fmaf(e, w[W5O + i * 3 + 1], c1);
            c2 = fmaf(e, w[W5O + i * 3 + 2], c2);
        }

        if (valid) {
            out[idx * 3 + 0] = 1.0f / (1.0f + __expf(-c0));
            out[idx * 3 + 1] = 1.0f / (1.0f + __expf(-c1));
            out[idx * 3 + 2] = 1.0f / (1.0f + __expf(-c2));
            out[3 * P + idx] = sigma;
        }
    }
}

extern "C" void kernel_launch(void* const* d_in, const int* in_sizes, int n_in,
                              void* d_out, int out_size, void* d_ws, size_t ws_size,
                              hipStream_t stream) {
    const float* xs = (const float*)d_in[0];
    const float* dv = (const float*)d_in[1];
    const float* w1 = (const float*)d_in[2];
    const float* b1 = (const float*)d_in[3];
    const float* w2 = (const float*)d_in[4];
    const float* b2 = (const float*)d_in[5];
    const float* w3 = (const float*)d_in[6];
    const float* b3 = (const float*)d_in[7];
    const float* w4 = (const float*)d_in[8];
    const float* b4 = (const float*)d_in[9];
    const float* w5 = (const float*)d_in[10];
    const float* b5 = (const float*)d_in[11];
    float* out = (float*)d_out;
    int P = in_sizes[0] / 3;

    // ws layout (ints): counts[4096] | offsets[4104] | cursor[4096] | sorted[P]
    int* counts = (int*)d_ws;
    int* offsets = counts + 4096;
    int* cursor = offsets + 4104;
    int* sorted = cursor + 4096;

    hipMemsetAsync(counts, 0, 4096 * sizeof(int), stream);

    int blk = 256;
    int grd = (P + blk - 1) / blk;
    k_count<<<grd, blk, 0, stream>>>(xs, counts, out, P);
    k_scan<<<1, 64, 0, stream>>>(counts, offsets, cursor);
    k_scatter<<<grd, blk, 0, stream>>>(xs, cursor, sorted, P);
    k_mlp<<<NCELL, 64, 0, stream>>>(xs, dv, w1, b1, w2, b2, w3, b3, w4, b4, w5, b5,
                                    offsets, sorted, out, P);
}

// Round 3
// 319.689 us; speedup vs baseline: 1.0002x; 1.0002x over previous
//
#include <hip/hip_runtime.h>

#define NCELL 4096

// LDS weight layout (float offsets, all segment starts 16B-aligned)
#define W1O 0      // 63x32 = 2016
#define B1O 2016   // 32
#define W2O 2048   // 32x33 = 1056
#define B2O 3104   // 33 (pad to 36)
#define W3O 3140   // 32x32 = 1024
#define B3O 4164   // 32
#define W4O 4196   // 59x32 = 1888
#define B4O 6084   // 32
#define W5O 6116   // 32x3 = 96
#define B5O 6212   // 3 (pad to 4)
#define WTOT 6216

__device__ __forceinline__ int cell_of(float x0, float x1, float x2) {
    int i0 = (int)(x0 / 0.1875f + 8.0f);
    int i1 = (int)(x1 / 0.1875f + 8.0f);
    int i2 = (int)(x2 / 0.1875f + 8.0f);
    i0 = i0 < 0 ? 0 : (i0 > 15 ? 15 : i0);
    i1 = i1 < 0 ? 0 : (i1 > 15 ? 15 : i1);
    i2 = i2 < 0 ? 0 : (i2 > 15 ? 15 : i2);
    return (i0 * 16 + i1) * 16 + i2;
}

// Kernel 1: count active points per cell; write zeros for masked points.
__global__ void k_count(const float* __restrict__ xs, int* __restrict__ counts,
                        float* __restrict__ out, int P) {
    int p = blockIdx.x * blockDim.x + threadIdx.x;
    if (p >= P) return;
    float x0 = xs[p * 3 + 0], x1 = xs[p * 3 + 1], x2 = xs[p * 3 + 2];
    bool m = (fabsf(x0) < 1.5f) && (fabsf(x1) < 1.5f) && (fabsf(x2) < 1.5f);
    if (m) {
        atomicAdd(&counts[cell_of(x0, x1, x2)], 1);
    } else {
        out[p * 3 + 0] = 0.0f;
        out[p * 3 + 1] = 0.0f;
        out[p * 3 + 2] = 0.0f;
        out[3 * P + p] = 0.0f;
    }
}

// Kernel 2: exclusive prefix sum over 4096 cell counts (one wave).
__global__ void k_scan(const int* __restrict__ counts, int* __restrict__ offsets,
                       int* __restrict__ cursor) {
    int l = threadIdx.x;
    int base = l * 64;
    int s = 0;
    for (int k = 0; k < 64; k++) s += counts[base + k];
    int incl = s;
    for (int d = 1; d < 64; d <<= 1) {
        int v = __shfl_up(incl, d, 64);
        if (l >= d) incl += v;
    }
    int run = incl - s;
    for (int k = 0; k < 64; k++) {
        offsets[base + k] = run;
        cursor[base + k] = run;
        run += counts[base + k];
    }
    if (l == 63) offsets[4096] = run;
}

// Kernel 3: scatter active point indices into per-cell contiguous ranges.
__global__ void k_scatter(const float* __restrict__ xs, int* __restrict__ cursor,
                          int* __restrict__ sorted, int P) {
    int p = blockIdx.x * blockDim.x + threadIdx.x;
    if (p >= P) return;
    float x0 = xs[p * 3 + 0], x1 = xs[p * 3 + 1], x2 = xs[p * 3 + 2];
    bool m = (fabsf(x0) < 1.5f) && (fabsf(x1) < 1.5f) && (fabsf(x2) < 1.5f);
    if (!m) return;
    int c = cell_of(x0, x1, x2);
    int pos = atomicAdd(&cursor[c], 1);
    sorted[pos] = p;
}

__device__ __forceinline__ void stage4(float* __restrict__ dst,
                                       const float* __restrict__ src,
                                       int n4, int tid) {
    float4* d = (float4*)dst;
    const float4* s = (const float4*)src;
    for (int k = tid; k < n4; k += 64) d[k] = s[k];
}

// Row-FMA helpers: consume one input feature immediately (no enc[] array).
#define ROW32(ACC, WBASE, i, e)                                           \
    {                                                                     \
        float _e = (e);                                                   \
        _Pragma("unroll") for (int _o = 0; _o < 32; _o++)                 \
            ACC[_o] = fmaf(_e, w[(WBASE) + (i) * 32 + _o], ACC[_o]);      \
    }
#define ROW33(ACC, WBASE, i, e)                                           \
    {                                                                     \
        float _e = (e);                                                   \
        _Pragma("unroll") for (int _o = 0; _o < 33; _o++)                 \
            ACC[_o] = fmaf(_e, w[(WBASE) + (i) * 33 + _o], ACC[_o]);      \
    }

// Kernel 4: one block (1 wave) per cell. Weights staged in LDS (coalesced
// float4); compute reads weights via uniform LDS broadcast. Encodings fused
// into the row loops so peak register liveness stays ~80 VGPRs (no spills).
__global__ void __launch_bounds__(64, 4) k_mlp(
    const float* __restrict__ xs, const float* __restrict__ dvs,
    const float* __restrict__ w1, const float* __restrict__ b1,
    const float* __restrict__ w2, const float* __restrict__ b2,
    const float* __restrict__ w3, const float* __restrict__ b3,
    const float* __restrict__ w4, const float* __restrict__ b4,
    const float* __restrict__ w5, const float* __restrict__ b5,
    const int* __restrict__ offsets, const int* __restrict__ sorted,
    float* __restrict__ out, int P) {
    __shared__ float w[WTOT];
    int cell = blockIdx.x;
    int start = offsets[cell], end = offsets[cell + 1];
    if (start >= end) return;
    int tid = threadIdx.x;

    stage4(&w[W1O], w1 + (size_t)cell * 2016, 504, tid);
    stage4(&w[B1O], b1 + (size_t)cell * 32, 8, tid);
    stage4(&w[W2O], w2 + (size_t)cell * 1056, 264, tid);
    for (int k = tid; k < 33; k += 64) w[B2O + k] = b2[(size_t)cell * 33 + k];
    stage4(&w[W3O], w3 + (size_t)cell * 1024, 256, tid);
    stage4(&w[B3O], b3 + (size_t)cell * 32, 8, tid);
    stage4(&w[W4O], w4 + (size_t)cell * 1888, 472, tid);
    stage4(&w[B4O], b4 + (size_t)cell * 32, 8, tid);
    stage4(&w[W5O], w5 + (size_t)cell * 96, 24, tid);
    if (tid < 3) w[B5O + tid] = b5[(size_t)cell * 3 + tid];
    __syncthreads();

    for (int t0 = start; t0 < end; t0 += 64) {
        int t = t0 + tid;
        bool valid = t < end;
        int idx = sorted[valid ? t : start];

        float x0 = xs[idx * 3 + 0], x1 = xs[idx * 3 + 1], x2 = xs[idx * 3 + 2];
        float d0 = dvs[idx * 3 + 0], d1 = dvs[idx * 3 + 1], d2 = dvs[idx * 3 + 2];

        float sigma;
        float ha[33];  // layer accumulator / activations (reused per layer)
        float hb[33];  // second buffer

        // ---- layer 1: 63 -> 32, relu (encoding fused)
#pragma unroll
        for (int o = 0; o < 32; o++) ha[o] = w[B1O + o];
        ROW32(ha, W1O, 0, x0)
        ROW32(ha, W1O, 1, x1)
        ROW32(ha, W1O, 2, x2)
#pragma unroll
        for (int j = 0; j < 10; j++) {
            float pw = (float)(1 << j);
            float a0 = pw * x0, a1 = pw * x1, a2 = pw * x2;
            ROW32(ha, W1O, 3 + 6 * j + 0, __sinf(a0))
            ROW32(ha, W1O, 3 + 6 * j + 1, __sinf(a1))
            ROW32(ha, W1O, 3 + 6 * j + 2, __sinf(a2))
            ROW32(ha, W1O, 6 + 6 * j + 0, __cosf(a0))
            ROW32(ha, W1O, 6 + 6 * j + 1, __cosf(a1))
            ROW32(ha, W1O, 6 + 6 * j + 2, __cosf(a2))
        }
#pragma unroll
        for (int o = 0; o < 32; o++) ha[o] = fmaxf(ha[o], 0.0f);

        // ---- layer 2: 32 -> 33, relu; [0] = sigma
#pragma unroll
        for (int o = 0; o < 33; o++) hb[o] = w[B2O + o];
#pragma unroll
        for (int i = 0; i < 32; i++) ROW33(hb, W2O, i, ha[i])
        sigma = fmaxf(hb[0], 0.0f);
#pragma unroll
        for (int o = 0; o < 32; o++) hb[o] = fmaxf(hb[o + 1], 0.0f);

        // ---- layer 3: 32 -> 32, no activation
#pragma unroll
        for (int o = 0; o < 32; o++) ha[o] = w[B3O + o];
#pragma unroll
        for (int i = 0; i < 32; i++) ROW32(ha, W3O, i, hb[i])

        // ---- layer 4: 59 (ha[0..31] ++ dir-enc 27 fused) -> 32, relu
#pragma unroll
        for (int o = 0; o < 32; o++) hb[o] = w[B4O + o];
#pragma unroll
        for (int i = 0; i < 32; i++) ROW32(hb, W4O, i, ha[i])
        ROW32(hb, W4O, 32, d0)
        ROW32(hb, W4O, 33, d1)
        ROW32(hb, W4O, 34, d2)
#pragma unroll
        for (int j = 0; j < 4; j++) {
            float pw = (float)(1 << j);
            float a0 = pw * d0, a1 = pw * d1, a2 = pw * d2;
            ROW32(hb, W4O, 35 + 6 * j + 0, __sinf(a0))
            ROW32(hb, W4O, 35 + 6 * j + 1, __sinf(a1))
            ROW32(hb, W4O, 35 + 6 * j + 2, __sinf(a2))
            ROW32(hb, W4O, 38 + 6 * j + 0, __cosf(a0))
            ROW32(hb, W4O, 38 + 6 * j + 1, __cosf(a1))
            ROW32(hb, W4O, 38 + 6 * j + 2, __cosf(a2))
        }
#pragma unroll
        for (int o = 0; o < 32; o++) hb[o] = fmaxf(hb[o], 0.0f);

        // ---- layer 5: 32 -> 3, sigmoid
        float c0 = w[B5O + 0], c1 = w[B5O + 1], c2 = w[B5O + 2];
#pragma unroll
        for (int i = 0; i < 32; i++) {
            float e = hb[i];
            c0 = fmaf(e, w[W5O + i * 3 + 0], c0);
            c1 = fmaf(e, w[W5O + i * 3 + 1], c1);
            c2 = fmaf(e, w[W5O + i * 3 + 2], c2);
        }

        if (valid) {
            out[idx * 3 + 0] = 1.0f / (1.0f + __expf(-c0));
            out[idx * 3 + 1] = 1.0f / (1.0f + __expf(-c1));
            out[idx * 3 + 2] = 1.0f / (1.0f + __expf(-c2));
            out[3 * P + idx] = sigma;
        }
    }
}

extern "C" void kernel_launch(void* const* d_in, const int* in_sizes, int n_in,
                              void* d_out, int out_size, void* d_ws, size_t ws_size,
                              hipStream_t stream) {
    const float* xs = (const float*)d_in[0];
    const float* dv = (const float*)d_in[1];
    const float* w1 = (const float*)d_in[2];
    const float* b1 = (const float*)d_in[3];
    const float* w2 = (const float*)d_in[4];
    const float* b2 = (const float*)d_in[5];
    const float* w3 = (const float*)d_in[6];
    const float* b3 = (const float*)d_in[7];
    const float* w4 = (const float*)d_in[8];
    const float* b4 = (const float*)d_in[9];
    const float* w5 = (const float*)d_in[10];
    const float* b5 = (const float*)d_in[11];
    float* out = (float*)d_out;
    int P = in_sizes[0] / 3;

    // ws layout (ints): counts[4096] | offsets[4104] | cursor[4096] | sorted[P]
    int* counts = (int*)d_ws;
    int* offsets = counts + 4096;
    int* cursor = offsets + 4104;
    int* sorted = cursor + 4096;

    hipMemsetAsync(counts, 0, 4096 * sizeof(int), stream);

    int blk = 256;
    int grd = (P + blk - 1) / blk;
    k_count<<<grd, blk, 0, stream>>>(xs, counts, out, P);
    k_scan<<<1, 64, 0, stream>>>(counts, offsets, cursor);
    k_scatter<<<grd, blk, 0, stream>>>(xs, cursor, sorted, P);
    k_mlp<<<NCELL, 64, 0, stream>>>(xs, dv, w1, b1, w2, b2, w3, b3, w4, b4, w5, b5,
                                    offsets, sorted, out, P);
}

// Round 4
// 227.340 us; speedup vs baseline: 1.4064x; 1.4062x over previous
//
#include <hip/hip_runtime.h>

#define NCELL 4096

// LDS weight layout (float offsets, segment starts 16B-aligned where staged as float4)
#define W1O 0      // 63x32 = 2016
#define B1O 2016   // 32
#define W2O 2048   // 32x33 = 1056
#define B2O 3104   // 33 (pad to 36)
#define W3O 3140   // 32x32 = 1024
#define B3O 4164   // 32
#define W4O 4196   // 59x32 = 1888
#define B4O 6084   // 32
#define W5O 6116   // 32x3 = 96
#define B5O 6212   // 3 (pad to 4)
#define WTOT 6216

__device__ __forceinline__ int cell_of(float x0, float x1, float x2) {
    int i0 = (int)(x0 / 0.1875f + 8.0f);
    int i1 = (int)(x1 / 0.1875f + 8.0f);
    int i2 = (int)(x2 / 0.1875f + 8.0f);
    i0 = i0 < 0 ? 0 : (i0 > 15 ? 15 : i0);
    i1 = i1 < 0 ? 0 : (i1 > 15 ? 15 : i1);
    i2 = i2 < 0 ? 0 : (i2 > 15 ? 15 : i2);
    return (i0 * 16 + i1) * 16 + i2;
}

// Kernel 1: count active points per cell; write zeros for masked points.
__global__ void k_count(const float* __restrict__ xs, int* __restrict__ counts,
                        float* __restrict__ out, int P) {
    int p = blockIdx.x * blockDim.x + threadIdx.x;
    if (p >= P) return;
    float x0 = xs[p * 3 + 0], x1 = xs[p * 3 + 1], x2 = xs[p * 3 + 2];
    bool m = (fabsf(x0) < 1.5f) && (fabsf(x1) < 1.5f) && (fabsf(x2) < 1.5f);
    if (m) {
        atomicAdd(&counts[cell_of(x0, x1, x2)], 1);
    } else {
        out[p * 3 + 0] = 0.0f;
        out[p * 3 + 1] = 0.0f;
        out[p * 3 + 2] = 0.0f;
        out[3 * P + p] = 0.0f;
    }
}

// Kernel 2: exclusive prefix sum over 4096 cell counts (one wave).
__global__ void k_scan(const int* __restrict__ counts, int* __restrict__ offsets,
                       int* __restrict__ cursor) {
    int l = threadIdx.x;
    int base = l * 64;
    int s = 0;
    for (int k = 0; k < 64; k++) s += counts[base + k];
    int incl = s;
    for (int d = 1; d < 64; d <<= 1) {
        int v = __shfl_up(incl, d, 64);
        if (l >= d) incl += v;
    }
    int run = incl - s;
    for (int k = 0; k < 64; k++) {
        offsets[base + k] = run;
        cursor[base + k] = run;
        run += counts[base + k];
    }
    if (l == 63) offsets[4096] = run;
}

// Kernel 3: scatter active point indices into per-cell contiguous ranges.
__global__ void k_scatter(const float* __restrict__ xs, int* __restrict__ cursor,
                          int* __restrict__ sorted, int P) {
    int p = blockIdx.x * blockDim.x + threadIdx.x;
    if (p >= P) return;
    float x0 = xs[p * 3 + 0], x1 = xs[p * 3 + 1], x2 = xs[p * 3 + 2];
    bool m = (fabsf(x0) < 1.5f) && (fabsf(x1) < 1.5f) && (fabsf(x2) < 1.5f);
    if (!m) return;
    int c = cell_of(x0, x1, x2);
    int pos = atomicAdd(&cursor[c], 1);
    sorted[pos] = p;
}

__device__ __forceinline__ void stage4(float* __restrict__ dst,
                                       const float* __restrict__ src,
                                       int n4, int tid) {
    float4* d = (float4*)dst;
    const float4* s = (const float4*)src;
    for (int k = tid; k < n4; k += 64) d[k] = s[k];
}

// Kernel 4: one block (1 wave) per cell. Weights staged once into LDS
// (coalesced float4, read-once from HBM); per-lane activations in LDS
// stride-63 slots (conflict-free); 32-33 register accumulators only.
// Row loops kept as runtime loops with unroll 2 -- this is the R1 structure
// that measured 68 VGPR / zero spill; only the weight source changed.
__global__ void __launch_bounds__(64) k_mlp(
    const float* __restrict__ xs, const float* __restrict__ dvs,
    const float* __restrict__ w1, const float* __restrict__ b1,
    const float* __restrict__ w2, const float* __restrict__ b2,
    const float* __restrict__ w3, const float* __restrict__ b3,
    const float* __restrict__ w4, const float* __restrict__ b4,
    const float* __restrict__ w5, const float* __restrict__ b5,
    const int* __restrict__ offsets, const int* __restrict__ sorted,
    float* __restrict__ out, int P) {
    __shared__ float w[WTOT];
    __shared__ float act[64 * 63];
    int cell = blockIdx.x;
    int start = offsets[cell], end = offsets[cell + 1];
    if (start >= end) return;
    int tid = threadIdx.x;

    stage4(&w[W1O], w1 + (size_t)cell * 2016, 504, tid);
    stage4(&w[B1O], b1 + (size_t)cell * 32, 8, tid);
    stage4(&w[W2O], w2 + (size_t)cell * 1056, 264, tid);
    for (int k = tid; k < 33; k += 64) w[B2O + k] = b2[(size_t)cell * 33 + k];
    stage4(&w[W3O], w3 + (size_t)cell * 1024, 256, tid);
    stage4(&w[B3O], b3 + (size_t)cell * 32, 8, tid);
    stage4(&w[W4O], w4 + (size_t)cell * 1888, 472, tid);
    stage4(&w[B4O], b4 + (size_t)cell * 32, 8, tid);
    stage4(&w[W5O], w5 + (size_t)cell * 96, 24, tid);
    if (tid < 3) w[B5O + tid] = b5[(size_t)cell * 3 + tid];
    __syncthreads();

    float* my = act + tid * 63;

    for (int t0 = start; t0 < end; t0 += 64) {
        int t = t0 + tid;
        bool valid = t < end;
        int idx = sorted[valid ? t : start];

        float x0 = xs[idx * 3 + 0], x1 = xs[idx * 3 + 1], x2 = xs[idx * 3 + 2];

        // positional encoding (63) into per-lane LDS slot
        my[0] = x0; my[1] = x1; my[2] = x2;
        float pw = 1.0f;
#pragma unroll
        for (int j = 0; j < 10; j++) {
            float a0 = pw * x0, a1 = pw * x1, a2 = pw * x2;
            my[3 + 6 * j + 0] = __sinf(a0);
            my[3 + 6 * j + 1] = __sinf(a1);
            my[3 + 6 * j + 2] = __sinf(a2);
            my[6 + 6 * j + 0] = __cosf(a0);
            my[6 + 6 * j + 1] = __cosf(a1);
            my[6 + 6 * j + 2] = __cosf(a2);
            pw *= 2.0f;
        }

        float h[33];
        // ---- layer 1: 63 -> 32, relu
#pragma unroll
        for (int o = 0; o < 32; o++) h[o] = w[B1O + o];
#pragma unroll 2
        for (int i = 0; i < 63; i++) {
            float e = my[i];
#pragma unroll
            for (int o = 0; o < 32; o++) h[o] = fmaf(e, w[W1O + i * 32 + o], h[o]);
        }
#pragma unroll
        for (int o = 0; o < 32; o++) my[o] = fmaxf(h[o], 0.0f);

        // ---- layer 2: 32 -> 33, relu; [0] = sigma
        float g[33];
#pragma unroll
        for (int o = 0; o < 33; o++) g[o] = w[B2O + o];
#pragma unroll 2
        for (int i = 0; i < 32; i++) {
            float e = my[i];
#pragma unroll
            for (int o = 0; o < 33; o++) g[o] = fmaf(e, w[W2O + i * 33 + o], g[o]);
        }
        float sigma = fmaxf(g[0], 0.0f);
#pragma unroll
        for (int o = 0; o < 32; o++) my[o] = fmaxf(g[o + 1], 0.0f);

        // ---- layer 3: 32 -> 32, no activation
#pragma unroll
        for (int o = 0; o < 32; o++) h[o] = w[B3O + o];
#pragma unroll 2
        for (int i = 0; i < 32; i++) {
            float e = my[i];
#pragma unroll
            for (int o = 0; o < 32; o++) h[o] = fmaf(e, w[W3O + i * 32 + o], h[o]);
        }
#pragma unroll
        for (int o = 0; o < 32; o++) my[o] = h[o];

        // ---- direction encoding (27) into my[32..58]
        float d0 = dvs[idx * 3 + 0], d1 = dvs[idx * 3 + 1], d2 = dvs[idx * 3 + 2];
        my[32] = d0; my[33] = d1; my[34] = d2;
        pw = 1.0f;
#pragma unroll
        for (int j = 0; j < 4; j++) {
            float a0 = pw * d0, a1 = pw * d1, a2 = pw * d2;
            my[35 + 6 * j + 0] = __sinf(a0);
            my[35 + 6 * j + 1] = __sinf(a1);
            my[35 + 6 * j + 2] = __sinf(a2);
            my[38 + 6 * j + 0] = __cosf(a0);
            my[38 + 6 * j + 1] = __cosf(a1);
            my[38 + 6 * j + 2] = __cosf(a2);
            pw *= 2.0f;
        }

        // ---- layer 4: 59 -> 32, relu
#pragma unroll
        for (int o = 0; o < 32; o++) h[o] = w[B4O + o];
#pragma unroll 2
        for (int i = 0; i < 59; i++) {
            float e = my[i];
#pragma unroll
            for (int o = 0; o < 32; o++) h[o] = fmaf(e, w[W4O + i * 32 + o], h[o]);
        }
#pragma unroll
        for (int o = 0; o < 32; o++) my[o] = fmaxf(h[o], 0.0f);

        // ---- layer 5: 32 -> 3, sigmoid
        float c0 = w[B5O + 0], c1 = w[B5O + 1], c2 = w[B5O + 2];
#pragma unroll 4
        for (int i = 0; i < 32; i++) {
            float e = my[i];
            c0 = fmaf(e, w[W5O + i * 3 + 0], c0);
            c1 = fmaf(e, w[W5O + i * 3 + 1], c1);
            c2 = fmaf(e, w[W5O + i * 3 + 2], c2);
        }

        if (valid) {
            out[idx * 3 + 0] = 1.0f / (1.0f + __expf(-c0));
            out[idx * 3 + 1] = 1.0f / (1.0f + __expf(-c1));
            out[idx * 3 + 2] = 1.0f / (1.0f + __expf(-c2));
            out[3 * P + idx] = sigma;
        }
    }
}

extern "C" void kernel_launch(void* const* d_in, const int* in_sizes, int n_in,
                              void* d_out, int out_size, void* d_ws, size_t ws_size,
                              hipStream_t stream) {
    const float* xs = (const float*)d_in[0];
    const float* dv = (const float*)d_in[1];
    const float* w1 = (const float*)d_in[2];
    const float* b1 = (const float*)d_in[3];
    const float* w2 = (const float*)d_in[4];
    const float* b2 = (const float*)d_in[5];
    const float* w3 = (const float*)d_in[6];
    const float* b3 = (const float*)d_in[7];
    const float* w4 = (const float*)d_in[8];
    const float* b4 = (const float*)d_in[9];
    const float* w5 = (const float*)d_in[10];
    const float* b5 = (const float*)d_in[11];
    float* out = (float*)d_out;
    int P = in_sizes[0] / 3;

    // ws layout (ints): counts[4096] | offsets[4104] | cursor[4096] | sorted[P]
    int* counts = (int*)d_ws;
    int* offsets = counts + 4096;
    int* cursor = offsets + 4104;
    int* sorted = cursor + 4096;

    hipMemsetAsync(counts, 0, 4096 * sizeof(int), stream);

    int blk = 256;
    int grd = (P + blk - 1) / blk;
    k_count<<<grd, blk, 0, stream>>>(xs, counts, out, P);
    k_scan<<<1, 64, 0, stream>>>(counts, offsets, cursor);
    k_scatter<<<grd, blk, 0, stream>>>(xs, cursor, sorted, P);
    k_mlp<<<NCELL, 64, 0, stream>>>(xs, dv, w1, b1, w2, b2, w3, b3, w4, b4, w5, b5,
                                    offsets, sorted, out, P);
}

// Round 5
// 133.314 us; speedup vs baseline: 2.3984x; 1.7053x over previous
//
#include <hip/hip_runtime.h>

#define NCELL 4096

// LDS weight layout (float offsets)
#define W1O 0      // 63x32 = 2016
#define B1O 2016   // 32
#define W2O 2048   // 32x33 = 1056
#define B2O 3104   // 33 (pad to 36)
#define W3O 3140   // 32x32 = 1024
#define B3O 4164   // 32
#define W4O 4196   // 59x32 = 1888
#define B4O 6084   // 32
#define W5O 6116   // 32x3 = 96
#define B5O 6212   // 3 (pad to 4)
#define WTOT 6216

__device__ __forceinline__ int cell_of(float x0, float x1, float x2) {
    int i0 = (int)(x0 / 0.1875f + 8.0f);
    int i1 = (int)(x1 / 0.1875f + 8.0f);
    int i2 = (int)(x2 / 0.1875f + 8.0f);
    i0 = i0 < 0 ? 0 : (i0 > 15 ? 15 : i0);
    i1 = i1 < 0 ? 0 : (i1 > 15 ? 15 : i1);
    i2 = i2 < 0 ? 0 : (i2 > 15 ? 15 : i2);
    return (i0 * 16 + i1) * 16 + i2;
}

__global__ void k_count(const float* __restrict__ xs, int* __restrict__ counts,
                        float* __restrict__ out, int P) {
    int p = blockIdx.x * blockDim.x + threadIdx.x;
    if (p >= P) return;
    float x0 = xs[p * 3 + 0], x1 = xs[p * 3 + 1], x2 = xs[p * 3 + 2];
    bool m = (fabsf(x0) < 1.5f) && (fabsf(x1) < 1.5f) && (fabsf(x2) < 1.5f);
    if (m) {
        atomicAdd(&counts[cell_of(x0, x1, x2)], 1);
    } else {
        out[p * 3 + 0] = 0.0f;
        out[p * 3 + 1] = 0.0f;
        out[p * 3 + 2] = 0.0f;
        out[3 * P + p] = 0.0f;
    }
}

__global__ void k_scan(const int* __restrict__ counts, int* __restrict__ offsets,
                       int* __restrict__ cursor) {
    int l = threadIdx.x;
    int base = l * 64;
    int s = 0;
    for (int k = 0; k < 64; k++) s += counts[base + k];
    int incl = s;
    for (int d = 1; d < 64; d <<= 1) {
        int v = __shfl_up(incl, d, 64);
        if (l >= d) incl += v;
    }
    int run = incl - s;
    for (int k = 0; k < 64; k++) {
        offsets[base + k] = run;
        cursor[base + k] = run;
        run += counts[base + k];
    }
    if (l == 63) offsets[4096] = run;
}

__global__ void k_scatter(const float* __restrict__ xs, int* __restrict__ cursor,
                          int* __restrict__ sorted, int P) {
    int p = blockIdx.x * blockDim.x + threadIdx.x;
    if (p >= P) return;
    float x0 = xs[p * 3 + 0], x1 = xs[p * 3 + 1], x2 = xs[p * 3 + 2];
    bool m = (fabsf(x0) < 1.5f) && (fabsf(x1) < 1.5f) && (fabsf(x2) < 1.5f);
    if (!m) return;
    int c = cell_of(x0, x1, x2);
    int pos = atomicAdd(&cursor[c], 1);
    sorted[pos] = p;
}

__device__ __forceinline__ void stage4(float* __restrict__ dst,
                                       const float* __restrict__ src,
                                       int n4, int tid, int nt) {
    float4* d = (float4*)dst;
    const float4* s = (const float4*)src;
    for (int k = tid; k < n4; k += nt) d[k] = s[k];
}

// 16-wide row FMA: this wave's output half (wo = 16*wid)
#define ROW16(ACC, BASE, E)                                                \
    {                                                                      \
        float _e = (E);                                                    \
        const float* _wr = &w[(BASE) + wo];                                \
        _Pragma("unroll") for (int _o = 0; _o < 16; _o++)                  \
            ACC[_o] = fmaf(_e, _wr[_o], ACC[_o]);                          \
    }

// One block (2 waves, 128 thr) per cell. Wave w computes output columns
// [16w,16w+16). Weights staged in LDS (float4 coalesced); activations in
// per-lane LDS slots of 33 floats (stride 33 -> 2-way alias, free).
// Encodings fused into row loops (runtime j loop, unroll 1 -> no spills).
__global__ void __launch_bounds__(128) k_mlp(
    const float* __restrict__ xs, const float* __restrict__ dvs,
    const float* __restrict__ w1, const float* __restrict__ b1,
    const float* __restrict__ w2, const float* __restrict__ b2,
    const float* __restrict__ w3, const float* __restrict__ b3,
    const float* __restrict__ w4, const float* __restrict__ b4,
    const float* __restrict__ w5, const float* __restrict__ b5,
    const int* __restrict__ offsets, const int* __restrict__ sorted,
    float* __restrict__ out, int P) {
    __shared__ float w[WTOT];
    __shared__ float act[64 * 33];
    int cell = blockIdx.x;
    int start = offsets[cell], end = offsets[cell + 1];
    if (start >= end) return;
    int tid = threadIdx.x;
    int lane = tid & 63;
    int wid = tid >> 6;
    int wo = wid << 4;

    stage4(&w[W1O], w1 + (size_t)cell * 2016, 504, tid, 128);
    stage4(&w[B1O], b1 + (size_t)cell * 32, 8, tid, 128);
    stage4(&w[W2O], w2 + (size_t)cell * 1056, 264, tid, 128);
    for (int k = tid; k < 33; k += 128) w[B2O + k] = b2[(size_t)cell * 33 + k];
    stage4(&w[W3O], w3 + (size_t)cell * 1024, 256, tid, 128);
    stage4(&w[B3O], b3 + (size_t)cell * 32, 8, tid, 128);
    stage4(&w[W4O], w4 + (size_t)cell * 1888, 472, tid, 128);
    stage4(&w[B4O], b4 + (size_t)cell * 32, 8, tid, 128);
    stage4(&w[W5O], w5 + (size_t)cell * 96, 24, tid, 128);
    if (tid < 3) w[B5O + tid] = b5[(size_t)cell * 3 + tid];
    __syncthreads();

    float* al = &act[lane * 33];

    for (int t0 = start; t0 < end; t0 += 64) {
        __syncthreads();  // protect act vs previous iter's L5 reads
        int t = t0 + lane;
        bool valid = t < end;
        int idx = sorted[valid ? t : start];

        float x0 = xs[idx * 3 + 0], x1 = xs[idx * 3 + 1], x2 = xs[idx * 3 + 2];
        float d0 = dvs[idx * 3 + 0], d1 = dvs[idx * 3 + 1], d2 = dvs[idx * 3 + 2];

        float acc[17];
        float sigma = 0.0f;

        // ---- layer 1: 63 -> 32 (this wave: 16), relu; pos-enc fused
#pragma unroll
        for (int o = 0; o < 16; o++) acc[o] = w[B1O + wo + o];
        ROW16(acc, W1O + 0 * 32, x0)
        ROW16(acc, W1O + 1 * 32, x1)
        ROW16(acc, W1O + 2 * 32, x2)
        float pw = 1.0f;
#pragma unroll 1
        for (int j = 0; j < 10; j++) {
            float a0 = pw * x0, a1 = pw * x1, a2 = pw * x2;
            int rb = W1O + (3 + 6 * j) * 32;
            ROW16(acc, rb + 0, __sinf(a0))
            ROW16(acc, rb + 32, __sinf(a1))
            ROW16(acc, rb + 64, __sinf(a2))
            ROW16(acc, rb + 96, __cosf(a0))
            ROW16(acc, rb + 128, __cosf(a1))
            ROW16(acc, rb + 160, __cosf(a2))
            pw *= 2.0f;
        }
#pragma unroll
        for (int o = 0; o < 16; o++) al[wo + o] = fmaxf(acc[o], 0.0f);
        __syncthreads();  // L1 act visible

        // ---- layer 2: 32 -> 33; wave w computes cols [16w, 16w+17)
        float g[17];
#pragma unroll
        for (int k = 0; k < 17; k++) g[k] = w[B2O + wo + k];
#pragma unroll 2
        for (int i = 0; i < 32; i++) {
            float e = al[i];
            const float* wr = &w[W2O + i * 33 + wo];
#pragma unroll
            for (int k = 0; k < 17; k++) g[k] = fmaf(e, wr[k], g[k]);
        }
        __syncthreads();  // all act reads done before overwrite
        if (wid == 0) {
            sigma = fmaxf(g[0], 0.0f);
#pragma unroll
            for (int k = 1; k < 17; k++) al[k - 1] = fmaxf(g[k], 0.0f);
        } else {
#pragma unroll
            for (int k = 0; k < 17; k++) al[15 + k] = fmaxf(g[k], 0.0f);
        }
        __syncthreads();

        // ---- layer 3: 32 -> 32, no activation
#pragma unroll
        for (int o = 0; o < 16; o++) acc[o] = w[B3O + wo + o];
#pragma unroll 2
        for (int i = 0; i < 32; i++) {
            float e = al[i];
            ROW16(acc, W3O + i * 32, e)
        }
        __syncthreads();
#pragma unroll
        for (int o = 0; o < 16; o++) al[wo + o] = acc[o];
        __syncthreads();

        // ---- layer 4: 59 -> 32, relu; dir-enc fused
#pragma unroll
        for (int o = 0; o < 16; o++) acc[o] = w[B4O + wo + o];
#pragma unroll 2
        for (int i = 0; i < 32; i++) {
            float e = al[i];
            ROW16(acc, W4O + i * 32, e)
        }
        __syncthreads();  // act reads done
        ROW16(acc, W4O + 32 * 32, d0)
        ROW16(acc, W4O + 33 * 32, d1)
        ROW16(acc, W4O + 34 * 32, d2)
        pw = 1.0f;
#pragma unroll 1
        for (int j = 0; j < 4; j++) {
            float a0 = pw * d0, a1 = pw * d1, a2 = pw * d2;
            int rb = W4O + (35 + 6 * j) * 32;
            ROW16(acc, rb + 0, __sinf(a0))
            ROW16(acc, rb + 32, __sinf(a1))
            ROW16(acc, rb + 64, __sinf(a2))
            ROW16(acc, rb + 96, __cosf(a0))
            ROW16(acc, rb + 128, __cosf(a1))
            ROW16(acc, rb + 160, __cosf(a2))
            pw *= 2.0f;
        }
#pragma unroll
        for (int o = 0; o < 16; o++) al[wo + o] = fmaxf(acc[o], 0.0f);
        __syncthreads();

        // ---- layer 5: 32 -> 3, sigmoid (wave 0 only)
        if (wid == 0) {
            float c0 = w[B5O + 0], c1 = w[B5O + 1], c2 = w[B5O + 2];
#pragma unroll 4
            for (int i = 0; i < 32; i++) {
                float e = al[i];
                c0 = fmaf(e, w[W5O + i * 3 + 0], c0);
                c1 = fmaf(e, w[W5O + i * 3 + 1], c1);
                c2 = fmaf(e, w[W5O + i * 3 + 2], c2);
            }
            if (valid) {
                out[idx * 3 + 0] = 1.0f / (1.0f + __expf(-c0));
                out[idx * 3 + 1] = 1.0f / (1.0f + __expf(-c1));
                out[idx * 3 + 2] = 1.0f / (1.0f + __expf(-c2));
                out[3 * P + idx] = sigma;
            }
        }
    }
}

extern "C" void kernel_launch(void* const* d_in, const int* in_sizes, int n_in,
                              void* d_out, int out_size, void* d_ws, size_t ws_size,
                              hipStream_t stream) {
    const float* xs = (const float*)d_in[0];
    const float* dv = (const float*)d_in[1];
    const float* w1 = (const float*)d_in[2];
    const float* b1 = (const float*)d_in[3];
    const float* w2 = (const float*)d_in[4];
    const float* b2 = (const float*)d_in[5];
    const float* w3 = (const float*)d_in[6];
    const float* b3 = (const float*)d_in[7];
    const float* w4 = (const float*)d_in[8];
    const float* b4 = (const float*)d_in[9];
    const float* w5 = (const float*)d_in[10];
    const float* b5 = (const float*)d_in[11];
    float* out = (float*)d_out;
    int P = in_sizes[0] / 3;

    int* counts = (int*)d_ws;
    int* offsets = counts + 4096;
    int* cursor = offsets + 4104;
    int* sorted = cursor + 4096;

    hipMemsetAsync(counts, 0, 4096 * sizeof(int), stream);

    int blk = 256;
    int grd = (P + blk - 1) / blk;
    k_count<<<grd, blk, 0, stream>>>(xs, counts, out, P);
    k_scan<<<1, 64, 0, stream>>>(counts, offsets, cursor);
    k_scatter<<<grd, blk, 0, stream>>>(xs, cursor, sorted, P);
    k_mlp<<<NCELL, 128, 0, stream>>>(xs, dv, w1, b1, w2, b2, w3, b3, w4, b4, w5, b5,
                                     offsets, sorted, out, P);
}